// Round 5
// baseline (365.227 us; speedup 1.0000x reference)
//
#include <hip/hip_runtime.h>
#include <math.h>

// Problem constants
#define Bb   256
#define Nn   16384
#define Dd   512
#define NNZn 540672
#define DFf  2048
#define SLOT 128   // padded CSR bucket width (row max ~58 << 128)

// k_prep block ranges (bucket first: latency-bound, overlaps BW-bound ranges)
#define BK_BLKS 528    // 540672 / 1024 (4 nnz per thread)
#define TR_BLKS 1024
#define CVT_BLKS 2048  // W_f1 + W_f2 only: 524288 vec4 / 256
#define MG_BLKS 64     // W_ov = W_o @ W_v  (512x512x512, 64x64 tiles)
#define BV_BLKS 2      // bsum = b_o + W_o @ b_v
#define BK0 0
#define TR0 (BK0 + BK_BLKS)
#define CVT0 (TR0 + TR_BLKS)
#define MG0 (CVT0 + CVT_BLKS)
#define BV0 (MG0 + MG_BLKS)
#define PREP_BLKS (BV0 + BV_BLKS)

typedef __bf16 bf16;
typedef __bf16 bf16x4 __attribute__((ext_vector_type(4)));
typedef __bf16 bf16x8 __attribute__((ext_vector_type(8)));
typedef float  f32x4  __attribute__((ext_vector_type(4)));

// ---------------------------------------------------------------- async G->LDS
__device__ __forceinline__ void gload16(const void* g, void* l) {
  __builtin_amdgcn_global_load_lds(
      (const __attribute__((address_space(1))) unsigned int*)g,
      (__attribute__((address_space(3))) unsigned int*)l, 16, 0, 0);
}

// ---- merged prep: nnz bucket | x0 transpose | FF-weight cvt | W_ov gemm | bsum
__global__ __launch_bounds__(256) void k_prep(
    const float* __restrict__ w_v, const float* __restrict__ w_o,
    const float* __restrict__ w_f1, const float* __restrict__ w_f2,
    bf16* __restrict__ o_f1, bf16* __restrict__ o_f2,
    bf16* __restrict__ w_ov,                       // out: 512x512 bf16 [d][j]
    const float* __restrict__ b_o, const float* __restrict__ b_v,
    float* __restrict__ bsum,                      // out: b_o + W_o@b_v
    const float* __restrict__ x0, bf16* __restrict__ x0T,
    const int* __restrict__ rows, const int* __restrict__ cols,
    const float* __restrict__ vals,
    int* __restrict__ counts, int2* __restrict__ ents) {
  __shared__ float tile[64][65];
  __shared__ __align__(16) bf16 As[64 * 32];
  __shared__ __align__(16) bf16 Bs[64 * 32];
  const int blk = blockIdx.x, tid = threadIdx.x;

  if (blk < TR0) {
    // ---- bucket: 4 nnz per thread, independent atomic+store chains
    int i0 = blk * 1024 + tid;
    int r[4], c[4]; float v[4];
#pragma unroll
    for (int q = 0; q < 4; q++) {
      int i = i0 + q * 256;
      r[q] = rows[i]; c[q] = cols[i]; v[q] = vals[i];
    }
    int p[4];
#pragma unroll
    for (int q = 0; q < 4; q++) p[q] = atomicAdd(&counts[r[q]], 1);
#pragma unroll
    for (int q = 0; q < 4; q++)
      if (p[q] < SLOT)
        ents[(size_t)r[q] * SLOT + p[q]] = make_int2(c[q], __float_as_int(v[q]));
  } else if (blk < CVT0) {
    // ---- x0 (B,N) fp32 -> x0T (N,B) bf16
    int bx = blk - TR0;
    int n0 = (bx & 255) * 64, b0 = (bx >> 8) * 64;
    int tx = tid & 63, ty = tid >> 6;
#pragma unroll
    for (int i = 0; i < 16; i++) {
      int bl = ty * 16 + i;
      tile[bl][tx] = x0[(size_t)(b0 + bl) * Nn + n0 + tx];
    }
    __syncthreads();
#pragma unroll
    for (int i = 0; i < 16; i++) {
      int nl = ty * 16 + i;
      x0T[(size_t)(n0 + nl) * Bb + b0 + tx] = (bf16)tile[tx][nl];
    }
  } else if (blk < MG0) {
    // ---- FF weights fp32 -> bf16
    int v4 = (blk - CVT0) * 256 + tid;  // 0..524287
    const float* s; bf16* d; int base;
    if (v4 < 262144) { s = w_f1; d = o_f1; base = 0; }
    else             { s = w_f2; d = o_f2; base = 262144; }
    int idx = (v4 - base) * 4;
    float4 x = *(const float4*)(s + idx);
    bf16x4 o;
    o[0] = (bf16)x.x; o[1] = (bf16)x.y; o[2] = (bf16)x.z; o[3] = (bf16)x.w;
    *(bf16x4*)(d + idx) = o;
  } else if (blk < BV0) {
    // ---- W_ov[d][j] = sum_e W_o[d][e] * W_v[e][j]  (64x64 tile per block)
    int mg = blk - MG0;
    int m0 = (mg >> 3) * 64, n0 = (mg & 7) * 64;
    const int lane = tid & 63, w = tid >> 6;
    const int wm = w >> 1, wn = w & 1;
    f32x4 acc[2][2];
#pragma unroll
    for (int i = 0; i < 2; i++)
#pragma unroll
      for (int j = 0; j < 2; j++) acc[i][j] = {0.f, 0.f, 0.f, 0.f};
    for (int e0 = 0; e0 < Dd; e0 += 32) {
      __syncthreads();
      // As[d][e] from W_o (e contiguous)
#pragma unroll
      for (int p = 0; p < 2; p++) {
        int u = p * 256 + tid;
        int row = u >> 3, sub = u & 7;
        float4 x = *(const float4*)(w_o + (size_t)(m0 + row) * Dd + e0 + sub * 4);
        bf16x4 o;
        o[0] = (bf16)x.x; o[1] = (bf16)x.y; o[2] = (bf16)x.z; o[3] = (bf16)x.w;
        *(bf16x4*)(As + row * 32 + sub * 4) = o;
      }
      // Bs[j][e] from W_v[e][j] (transpose during staging)
#pragma unroll
      for (int p = 0; p < 2; p++) {
        int u = p * 256 + tid;
        int el = u >> 4, jq = u & 15;
        float4 x = *(const float4*)(w_v + (size_t)(e0 + el) * Dd + n0 + jq * 4);
        Bs[(jq * 4 + 0) * 32 + el] = (bf16)x.x;
        Bs[(jq * 4 + 1) * 32 + el] = (bf16)x.y;
        Bs[(jq * 4 + 2) * 32 + el] = (bf16)x.z;
        Bs[(jq * 4 + 3) * 32 + el] = (bf16)x.w;
      }
      __syncthreads();
      bf16x8 af[2], bfr[2];
#pragma unroll
      for (int i = 0; i < 2; i++)
        af[i] = *(const bf16x8*)(As + (wm * 32 + i * 16 + (lane & 15)) * 32 + (lane >> 4) * 8);
#pragma unroll
      for (int j = 0; j < 2; j++)
        bfr[j] = *(const bf16x8*)(Bs + (wn * 32 + j * 16 + (lane & 15)) * 32 + (lane >> 4) * 8);
#pragma unroll
      for (int i = 0; i < 2; i++)
#pragma unroll
        for (int j = 0; j < 2; j++)
          acc[i][j] = __builtin_amdgcn_mfma_f32_16x16x32_bf16(af[i], bfr[j], acc[i][j], 0, 0, 0);
    }
#pragma unroll
    for (int i = 0; i < 2; i++)
#pragma unroll
      for (int j = 0; j < 2; j++) {
        int jj = n0 + wn * 32 + j * 16 + (lane & 15);
        int dB = m0 + wm * 32 + i * 16 + ((lane >> 4) << 2);
#pragma unroll
        for (int r = 0; r < 4; r++)
          w_ov[(size_t)(dB + r) * Dd + jj] = (bf16)acc[i][j][r];
      }
  } else {
    // ---- bsum[d] = b_o[d] + sum_e W_o[d][e] * b_v[e]
    int d = (blk - BV0) * 256 + tid;
    float s = b_o[d];
    for (int e = 0; e < Dd; e += 4) {
      float4 wo = *(const float4*)(w_o + (size_t)d * Dd + e);
      float4 bv = *(const float4*)(b_v + e);
      s += wo.x * bv.x + wo.y * bv.y + wo.z * bv.z + wo.w * bv.w;
    }
    bsum[d] = s;
  }
}

// ---- Lx[r][:] = sum_j val_j * x0T[col_j][:].  One WAVE per row; lane holds
// 4 batch elems (bf16x4) -> one gather = full 512 B row. 4-way unroll (MLP).
__global__ __launch_bounds__(256) void k_lx(const bf16x4* __restrict__ x0T4,
                                            const int* __restrict__ counts,
                                            const int2* __restrict__ ents,
                                            bf16x4* __restrict__ Lx4) {
  int w = threadIdx.x >> 6, lane = threadIdx.x & 63;
  int r = blockIdx.x * 4 + w;
  __shared__ int2 esm[4][64];
  int cnt = counts[r];
  const int2* ep = ents + (size_t)r * SLOT;
  f32x4 a = {0.f, 0.f, 0.f, 0.f}, b = {0.f, 0.f, 0.f, 0.f};
  f32x4 c = {0.f, 0.f, 0.f, 0.f}, d = {0.f, 0.f, 0.f, 0.f};
  for (int base = 0; base < cnt; base += 64) {
    int m = cnt - base; if (m > 64) m = 64;
    if (lane < m) esm[w][lane] = ep[base + lane];
    int i = 0;
    for (; i + 3 < m; i += 4) {
      int2 e0 = esm[w][i], e1 = esm[w][i + 1], e2 = esm[w][i + 2], e3 = esm[w][i + 3];
      bf16x4 x0v = x0T4[(size_t)e0.x * 64 + lane];
      bf16x4 x1v = x0T4[(size_t)e1.x * 64 + lane];
      bf16x4 x2v = x0T4[(size_t)e2.x * 64 + lane];
      bf16x4 x3v = x0T4[(size_t)e3.x * 64 + lane];
      float v0 = __int_as_float(e0.y), v1 = __int_as_float(e1.y);
      float v2 = __int_as_float(e2.y), v3 = __int_as_float(e3.y);
#pragma unroll
      for (int q = 0; q < 4; q++) {
        a[q] += v0 * (float)x0v[q];
        b[q] += v1 * (float)x1v[q];
        c[q] += v2 * (float)x2v[q];
        d[q] += v3 * (float)x3v[q];
      }
    }
    for (; i < m; i++) {
      int2 e0 = esm[w][i];
      bf16x4 x0v = x0T4[(size_t)e0.x * 64 + lane];
      float v0 = __int_as_float(e0.y);
#pragma unroll
      for (int q = 0; q < 4; q++) a[q] += v0 * (float)x0v[q];
    }
  }
  bf16x4 o;
#pragma unroll
  for (int q = 0; q < 4; q++) o[q] = (bf16)(a[q] + b[q] + c[q] + d[q]);
  Lx4[(size_t)r * 64 + lane] = o;
}

// ---------------- x_t[b][n] = x0[b][n] - 0.5*t[b]*Lx[n][b]   (bf16, B-major)
__global__ __launch_bounds__(256) void k_combine(const float* __restrict__ x0,
                                                 const bf16* __restrict__ Lx,
                                                 const float* __restrict__ t,
                                                 bf16* __restrict__ xt) {
  __shared__ float lxs[64][65];
  int n0 = blockIdx.x * 64, b0 = blockIdx.y * 64;
  int tx = threadIdx.x & 63, ty = threadIdx.x >> 6;
#pragma unroll
  for (int i = 0; i < 16; i++) {
    int nl = ty * 16 + i;
    lxs[nl][tx] = (float)Lx[(size_t)(n0 + nl) * Bb + b0 + tx];
  }
  __syncthreads();
#pragma unroll
  for (int i = 0; i < 16; i++) {
    int bl = ty * 16 + i;
    int b  = b0 + bl;
    float tc = t[b] * 0.5f;   // T_MAX
    float v = x0[(size_t)b * Nn + n0 + tx] - tc * lxs[tx][bl];
    xt[(size_t)b * Nn + n0 + tx] = (bf16)v;
  }
}

// ------------------------------------------------------------- bf16 TN GEMM
// C[m][n] = sum_k A[m][k]*Bm[n][k].
//   MODE 0: store fp32 split-K partial at z*MN
//   MODE 1: direct bf16 store of acc+bias (ACT=1: exact gelu) -> C is bf16*
//   MODE 2: fused loss sum((C+bias-x0)^2), last wave writes final mean
//   BF32 : B matrix is fp32 in global; convert to bf16 during LDS staging
template <int BM, int BN, int MODE, int ACT = 0, int BF32 = 0>
__global__ __launch_bounds__(256) void gemm_tn(
    const bf16* __restrict__ A, const void* __restrict__ Bmv,
    float* __restrict__ C, int N, int K, int kLen, int MN,
    const float* __restrict__ bias, const float* __restrict__ x0,
    float* __restrict__ lossOut, float* __restrict__ finalOut, int nWaves) {
  constexpr int WM = BM / 2, WN = BN / 2, FM = WM / 16, FN = WN / 16;
  constexpr int PA = (BM * 64) / 4096, PB = (BN * 64) / 4096;
  __shared__ __align__(16) bf16 As[BM * 32];
  __shared__ __align__(16) bf16 Bs[BN * 32];
  const int tid = threadIdx.x;
  const int lane = tid & 63, w = tid >> 6;
  const int wm = w >> 1, wn = w & 1;
  const int mBase = blockIdx.x * BM, nBase = blockIdx.y * BN;
  const int k0 = blockIdx.z * kLen;

  f32x4 acc[FM][FN];
#pragma unroll
  for (int i = 0; i < FM; i++)
#pragma unroll
    for (int j = 0; j < FN; j++) acc[i][j] = {0.f, 0.f, 0.f, 0.f};

  for (int kk = 0; kk < kLen; kk += 32) {
    const int k = k0 + kk;
    __syncthreads();
#pragma unroll
    for (int p = 0; p < PA; p++) {
      int u = p * 256 + tid;  // == p*256 + w*64 + lane
      gload16(A + (size_t)(mBase + (u >> 2)) * K + k + (u & 3) * 8,
              (char*)As + p * 4096 + w * 1024);
    }
    if constexpr (BF32) {
      const float* Bf = (const float*)Bmv;
#pragma unroll
      for (int p = 0; p < BN * 32 / 1024; p++) {
        int u = p * 256 + tid;
        int row = u >> 3, sub = u & 7;
        float4 x = *(const float4*)(Bf + (size_t)(nBase + row) * K + k + sub * 4);
        bf16x4 o;
        o[0] = (bf16)x.x; o[1] = (bf16)x.y; o[2] = (bf16)x.z; o[3] = (bf16)x.w;
        *(bf16x4*)(Bs + row * 32 + sub * 4) = o;
      }
    } else {
      const bf16* Bm = (const bf16*)Bmv;
#pragma unroll
      for (int p = 0; p < PB; p++) {
        int u = p * 256 + tid;
        gload16(Bm + (size_t)(nBase + (u >> 2)) * K + k + (u & 3) * 8,
                (char*)Bs + p * 4096 + w * 1024);
      }
    }
    __syncthreads();
    bf16x8 af[FM], bfr[FN];
#pragma unroll
    for (int i = 0; i < FM; i++)
      af[i] = *(const bf16x8*)(As + (wm * WM + i * 16 + (lane & 15)) * 32 + (lane >> 4) * 8);
#pragma unroll
    for (int j = 0; j < FN; j++)
      bfr[j] = *(const bf16x8*)(Bs + (wn * WN + j * 16 + (lane & 15)) * 32 + (lane >> 4) * 8);
#pragma unroll
    for (int i = 0; i < FM; i++)
#pragma unroll
      for (int j = 0; j < FN; j++)
        acc[i][j] = __builtin_amdgcn_mfma_f32_16x16x32_bf16(af[i], bfr[j], acc[i][j], 0, 0, 0);
  }

  if constexpr (MODE == 0) {
    float* Cz = C + (size_t)blockIdx.z * MN;
#pragma unroll
    for (int i = 0; i < FM; i++)
#pragma unroll
      for (int j = 0; j < FN; j++) {
        int n  = nBase + wn * WN + j * 16 + (lane & 15);
        int mB = mBase + wm * WM + i * 16 + ((lane >> 4) << 2);
#pragma unroll
        for (int r = 0; r < 4; r++)
          Cz[(size_t)(mB + r) * N + n] = acc[i][j][r];
      }
  } else if constexpr (MODE == 1) {
    bf16* Cb = (bf16*)C;
#pragma unroll
    for (int i = 0; i < FM; i++)
#pragma unroll
      for (int j = 0; j < FN; j++) {
        int n  = nBase + wn * WN + j * 16 + (lane & 15);
        float bo = bias[n];
        int mB = mBase + wm * WM + i * 16 + ((lane >> 4) << 2);
#pragma unroll
        for (int r = 0; r < 4; r++) {
          float x = acc[i][j][r] + bo;
          if constexpr (ACT == 1)
            x = 0.5f * x * (1.f + erff(x * 0.70710678118654752f));
          Cb[(size_t)(mB + r) * N + n] = (bf16)x;
        }
      }
  } else {
    float lsum = 0.f;
#pragma unroll
    for (int i = 0; i < FM; i++)
#pragma unroll
      for (int j = 0; j < FN; j++) {
        int n  = nBase + wn * WN + j * 16 + (lane & 15);
        float bo = bias[n];
        int mB = mBase + wm * WM + i * 16 + ((lane >> 4) << 2);
#pragma unroll
        for (int r = 0; r < 4; r++) {
          float d = acc[i][j][r] + bo - x0[(size_t)(mB + r) * N + n];
          lsum += d * d;
        }
      }
    for (int off = 32; off > 0; off >>= 1) lsum += __shfl_down(lsum, off, 64);
    if (lane == 0) {
      atomicAdd(lossOut, lsum);
      __threadfence();
      unsigned prev = atomicAdd((unsigned*)(lossOut + 1), 1u);
      if ((int)prev == nWaves - 1) {
        float tot = atomicAdd(lossOut, 0.f);  // atomic read-back
        finalOut[0] = tot * (1.f / 4194304.f);
      }
    }
  }
}

// ------------- h = sum_NS partials + b_in + time-embed; write fp32 + bf16
template <int NS>
__global__ __launch_bounds__(512) void k_epi_h(const float* __restrict__ P,
                                               const float* __restrict__ t,
                                               const float* __restrict__ W_t1,
                                               const float* __restrict__ b_t1,
                                               const float* __restrict__ W_t2,
                                               const float* __restrict__ b_t2,
                                               const float* __restrict__ b_in,
                                               float* __restrict__ h_f32,
                                               bf16* __restrict__ h_b) {
  int b = blockIdx.x, d = threadIdx.x;
  __shared__ float s[32];
  if (d < 32) {
    float z = t[b] * W_t1[d] + b_t1[d];   // t_norm == t
    s[d] = z / (1.f + expf(-z));          // silu
  }
  __syncthreads();
  int i = b * Dd + d;
  float v = b_in[d] + b_t2[d];
#pragma unroll
  for (int sp = 0; sp < NS; sp++) v += P[sp * (Bb * Dd) + i];
#pragma unroll
  for (int j = 0; j < 32; j++) v += s[j] * W_t2[d * 32 + j];
  h_f32[i] = v;
  h_b[i] = (bf16)v;
}

// -------- LayerNorm over D=512: x = base + sum_NS add + bias; y = LN(x)*g+be
template <int NS>
__global__ __launch_bounds__(512) void k_ln(const float* __restrict__ base,
                                            const float* __restrict__ add,
                                            const float* __restrict__ bias,
                                            const float* __restrict__ g,
                                            const float* __restrict__ be,
                                            float* __restrict__ out_f32,
                                            bf16* __restrict__ out_b) {
  int b = blockIdx.x, d = threadIdx.x;
  __shared__ float red[16];
  int i = b * Dd + d;
  float x = base[i] + bias[d];
#pragma unroll
  for (int sp = 0; sp < NS; sp++) x += add[sp * (Bb * Dd) + i];
  int w = d >> 6, lane = d & 63;
  float s = x;
  for (int off = 32; off > 0; off >>= 1) s += __shfl_down(s, off, 64);
  if (lane == 0) red[w] = s;
  __syncthreads();
  if (d == 0) {
    float tot = 0.f;
    for (int q = 0; q < 8; q++) tot += red[q];
    red[8] = tot * (1.f / 512.f);
  }
  __syncthreads();
  float mu = red[8];
  float c = x - mu;
  float s2 = c * c;
  for (int off = 32; off > 0; off >>= 1) s2 += __shfl_down(s2, off, 64);
  if (lane == 0) red[w] = s2;
  __syncthreads();
  if (d == 0) {
    float tot = 0.f;
    for (int q = 0; q < 8; q++) tot += red[q];
    red[8] = tot * (1.f / 512.f);
  }
  __syncthreads();
  float var = red[8];
  float y = c * rsqrtf(var + 1e-5f) * g[d] + be[d];
  if (out_f32) out_f32[i] = y;
  out_b[i] = (bf16)y;
}

// ======================================================================= host
extern "C" void kernel_launch(void* const* d_in, const int* in_sizes, int n_in,
                              void* d_out, int out_size, void* d_ws, size_t ws_size,
                              hipStream_t stream) {
  const float* x0    = (const float*)d_in[0];
  const float* t     = (const float*)d_in[1];
  const float* Lv    = (const float*)d_in[2];
  const float* W_in  = (const float*)d_in[3];
  const float* b_in  = (const float*)d_in[4];
  const float* W_out = (const float*)d_in[5];
  const float* b_out = (const float*)d_in[6];
  const float* W_qkv = (const float*)d_in[7];
  const float* b_qkv = (const float*)d_in[8];
  const float* W_o   = (const float*)d_in[9];
  const float* b_o   = (const float*)d_in[10];
  const float* g1    = (const float*)d_in[11];
  const float* be1   = (const float*)d_in[12];
  const float* g2    = (const float*)d_in[13];
  const float* be2   = (const float*)d_in[14];
  const float* W_f1  = (const float*)d_in[15];
  const float* b_f1  = (const float*)d_in[16];
  const float* W_f2  = (const float*)d_in[17];
  const float* b_f2  = (const float*)d_in[18];
  const float* W_t1  = (const float*)d_in[19];
  const float* b_t1  = (const float*)d_in[20];
  const float* W_t2  = (const float*)d_in[21];
  const float* b_t2  = (const float*)d_in[22];
  const int* L_rows  = (const int*)d_in[23];
  const int* L_cols  = (const int*)d_in[24];

  size_t off = 0;
  char* ws = (char*)d_ws;
  auto carve = [&](size_t bytes) -> void* {
    void* p = ws + off;
    off += (bytes + 255) & ~(size_t)255;
    return p;
  };

  bf16* W_ov_b   = (bf16*)carve((size_t)Dd * Dd * 2);
  bf16* W_f1_b   = (bf16*)carve((size_t)DFf * Dd * 2);
  bf16* W_f2_b   = (bf16*)carve((size_t)Dd * DFf * 2);
  float* bsum    = (float*)carve((size_t)Dd * 4);
  bf16* x0T_b    = (bf16*)carve((size_t)Nn * Bb * 2);
  bf16* Lx_b     = (bf16*)carve((size_t)Nn * Bb * 2);
  bf16* xt_b     = (bf16*)carve((size_t)Bb * Nn * 2);
  float* p_h     = (float*)carve((size_t)16 * Bb * Dd * 4);   // 8 MB
  float* p_at    = (float*)carve((size_t)Bb * Dd * 4);        // 0.5 MB
  float* p_f2    = (float*)carve((size_t)4 * Bb * Dd * 4);    // 2 MB
  float* h_f32   = (float*)carve((size_t)Bb * Dd * 4);
  bf16* h_b      = (bf16*)carve((size_t)Bb * Dd * 2);
  float* hln_f32 = (float*)carve((size_t)Bb * Dd * 4);
  bf16* hln_b    = (bf16*)carve((size_t)Bb * Dd * 2);
  bf16* f1_b     = (bf16*)carve((size_t)Bb * DFf * 2);
  bf16* h2_b     = (bf16*)carve((size_t)Bb * Dd * 2);
  int* counts    = (int*)carve((size_t)Nn * 4);
  float* lossw   = (float*)carve(256);                        // [0]=sum [1]=ticket
  int2* ents     = (int2*)carve((size_t)Nn * SLOT * 8);       // 16.8 MB
  (void)in_sizes; (void)n_in; (void)out_size; (void)ws_size; (void)Lv;

  // counts + lossw adjacent: one memset covers both
  hipMemsetAsync(counts, 0, (size_t)Nn * 4 + 256, stream);

  // prep: bucket | transpose | FF cvt | W_ov mini-gemm | bsum (one kernel)
  k_prep<<<PREP_BLKS, 256, 0, stream>>>(
      W_qkv + (size_t)2 * Dd * Dd, W_o, W_f1, W_f2, W_f1_b, W_f2_b,
      W_ov_b, b_o, b_qkv + 2 * Dd, bsum,
      x0, x0T_b, L_rows, L_cols, Lv, counts, ents);

  k_lx<<<Nn / 4, 256, 0, stream>>>((const bf16x4*)x0T_b, counts, ents,
                                   (bf16x4*)Lx_b);
  k_combine<<<dim3(256, 4), 256, 0, stream>>>(x0, Lx_b, t, xt_b);

  // h = x_t @ W_in^T   (M=256,N=512,K=16384, split-K=16, fp32-B staging)
  gemm_tn<128, 128, 0, 0, 1><<<dim3(2, 4, 16), 256, 0, stream>>>(
      xt_b, W_in, p_h, Dd, Nn, 1024, Bb * Dd, nullptr, nullptr, nullptr, nullptr, 0);
  k_epi_h<16><<<Bb, 512, 0, stream>>>(p_h, t, W_t1, b_t1, W_t2, b_t2, b_in,
                                      h_f32, h_b);

  // attn = h @ W_ov^T  (v- and o-proj fused; bias folded into bsum)
  gemm_tn<64, 64, 0><<<dim3(4, 8, 1), 256, 0, stream>>>(
      h_b, W_ov_b, p_at, Dd, Dd, 512, 0, nullptr, nullptr, nullptr, nullptr, 0);
  k_ln<1><<<Bb, 512, 0, stream>>>(h_f32, p_at, bsum, g1, be1, hln_f32, hln_b);

  // ff1 = gelu(hln @ W_f1^T + b_f1)  (fused bf16 epilogue)
  gemm_tn<64, 64, 1, 1><<<dim3(4, 32, 1), 256, 0, stream>>>(
      hln_b, W_f1_b, (float*)f1_b, DFf, Dd, 512, 0, b_f1, nullptr, nullptr, nullptr, 0);

  // ff2 = ff1 @ W_f2^T  (K=2048, split-K=4)
  gemm_tn<64, 64, 0><<<dim3(4, 8, 4), 256, 0, stream>>>(
      f1_b, W_f2_b, p_f2, Dd, DFf, 512, Bb * Dd, nullptr, nullptr, nullptr, nullptr, 0);
  k_ln<4><<<Bb, 512, 0, stream>>>(hln_f32, p_f2, b_f2, g2, be2, nullptr, h2_b);

  // pred = h2 @ W_out^T + b_out, fused loss + final mean (ticket finish)
  gemm_tn<128, 128, 2, 0, 1><<<dim3(2, 128, 1), 256, 0, stream>>>(
      h2_b, W_out, nullptr, Nn, Dd, 512, 0, b_out, x0, lossw,
      (float*)d_out, 2 * 128 * 4);
}

// Round 6
// 338.861 us; speedup vs baseline: 1.0778x; 1.0778x over previous
//
#include <hip/hip_runtime.h>
#include <math.h>

// Problem constants
#define Bb   256
#define Nn   16384
#define Dd   512
#define NNZn 540672
#define DFf  2048
#define SLOT 128   // padded CSR bucket width (row max ~58 << 128)

// k_prep block ranges (bucket first: latency-bound, overlaps BW-bound ranges)
#define BK_BLKS 528    // 540672 / 1024 (4 nnz per thread)
#define TR_BLKS 1024
#define CVT_BLKS 2048  // W_f1 + W_f2 only: 524288 vec4 / 256
#define MG_BLKS 64     // W_ov = W_o @ W_v  (512x512x512, 64x64 tiles)
#define BV_BLKS 2      // bsum = b_o + W_o @ b_v
#define BK0 0
#define TR0 (BK0 + BK_BLKS)
#define CVT0 (TR0 + TR_BLKS)
#define MG0 (CVT0 + CVT_BLKS)
#define BV0 (MG0 + MG_BLKS)
#define PREP_BLKS (BV0 + BV_BLKS)

typedef __bf16 bf16;
typedef __bf16 bf16x4 __attribute__((ext_vector_type(4)));
typedef __bf16 bf16x8 __attribute__((ext_vector_type(8)));
typedef float  f32x4  __attribute__((ext_vector_type(4)));

// ---------------------------------------------------------------- async G->LDS
__device__ __forceinline__ void gload16(const void* g, void* l) {
  __builtin_amdgcn_global_load_lds(
      (const __attribute__((address_space(1))) unsigned int*)g,
      (__attribute__((address_space(3))) unsigned int*)l, 16, 0, 0);
}

// ---- merged prep: nnz bucket | x0 transpose | FF-weight cvt | W_ov gemm | bsum
// LDS: single 16.6 KB arena aliased by the branches (they never coexist in a
// block) -- keeps occupancy at 9 blocks/CU (25 KB union cost us 34% occ in r5).
__global__ __launch_bounds__(256) void k_prep(
    const float* __restrict__ w_v, const float* __restrict__ w_o,
    const float* __restrict__ w_f1, const float* __restrict__ w_f2,
    bf16* __restrict__ o_f1, bf16* __restrict__ o_f2,
    bf16* __restrict__ w_ov,                       // out: 512x512 bf16 [d][j]
    const float* __restrict__ b_o, const float* __restrict__ b_v,
    float* __restrict__ bsum,                      // out: b_o + W_o@b_v
    const float* __restrict__ x0, bf16* __restrict__ x0T,
    const int* __restrict__ rows, const int* __restrict__ cols,
    const float* __restrict__ vals,
    int* __restrict__ counts, int2* __restrict__ ents) {
  __shared__ __align__(16) char smem[16640];
  const int blk = blockIdx.x, tid = threadIdx.x;

  if (blk < TR0) {
    // ---- bucket: 4 nnz per thread, independent atomic+store chains
    int i0 = blk * 1024 + tid;
    int r[4], c[4]; float v[4];
#pragma unroll
    for (int q = 0; q < 4; q++) {
      int i = i0 + q * 256;
      r[q] = rows[i]; c[q] = cols[i]; v[q] = vals[i];
    }
    int p[4];
#pragma unroll
    for (int q = 0; q < 4; q++) p[q] = atomicAdd(&counts[r[q]], 1);
#pragma unroll
    for (int q = 0; q < 4; q++)
      if (p[q] < SLOT)
        ents[(size_t)r[q] * SLOT + p[q]] = make_int2(c[q], __float_as_int(v[q]));
  } else if (blk < CVT0) {
    // ---- x0 (B,N) fp32 -> x0T (N,B) bf16
    float (*tile)[65] = (float(*)[65])smem;
    int bx = blk - TR0;
    int n0 = (bx & 255) * 64, b0 = (bx >> 8) * 64;
    int tx = tid & 63, ty = tid >> 6;
#pragma unroll
    for (int i = 0; i < 16; i++) {
      int bl = ty * 16 + i;
      tile[bl][tx] = x0[(size_t)(b0 + bl) * Nn + n0 + tx];
    }
    __syncthreads();
#pragma unroll
    for (int i = 0; i < 16; i++) {
      int nl = ty * 16 + i;
      x0T[(size_t)(n0 + nl) * Bb + b0 + tx] = (bf16)tile[tx][nl];
    }
  } else if (blk < MG0) {
    // ---- FF weights fp32 -> bf16
    int v4 = (blk - CVT0) * 256 + tid;  // 0..524287
    const float* s; bf16* d; int base;
    if (v4 < 262144) { s = w_f1; d = o_f1; base = 0; }
    else             { s = w_f2; d = o_f2; base = 262144; }
    int idx = (v4 - base) * 4;
    float4 x = *(const float4*)(s + idx);
    bf16x4 o;
    o[0] = (bf16)x.x; o[1] = (bf16)x.y; o[2] = (bf16)x.z; o[3] = (bf16)x.w;
    *(bf16x4*)(d + idx) = o;
  } else if (blk < BV0) {
    // ---- W_ov[d][j] = sum_e W_o[d][e] * W_v[e][j]  (64x64 tile per block)
    bf16* As = (bf16*)smem;
    bf16* Bs = (bf16*)(smem + 4096);
    int mg = blk - MG0;
    int m0 = (mg >> 3) * 64, n0 = (mg & 7) * 64;
    const int lane = tid & 63, w = tid >> 6;
    const int wm = w >> 1, wn = w & 1;
    f32x4 acc[2][2];
#pragma unroll
    for (int i = 0; i < 2; i++)
#pragma unroll
      for (int j = 0; j < 2; j++) acc[i][j] = {0.f, 0.f, 0.f, 0.f};
    for (int e0 = 0; e0 < Dd; e0 += 32) {
      __syncthreads();
      // As[d][e] from W_o (e contiguous)
#pragma unroll
      for (int p = 0; p < 2; p++) {
        int u = p * 256 + tid;
        int row = u >> 3, sub = u & 7;
        float4 x = *(const float4*)(w_o + (size_t)(m0 + row) * Dd + e0 + sub * 4);
        bf16x4 o;
        o[0] = (bf16)x.x; o[1] = (bf16)x.y; o[2] = (bf16)x.z; o[3] = (bf16)x.w;
        *(bf16x4*)(As + row * 32 + sub * 4) = o;
      }
      // Bs[j][e] from W_v[e][j] (transpose during staging)
#pragma unroll
      for (int p = 0; p < 2; p++) {
        int u = p * 256 + tid;
        int el = u >> 4, jq = u & 15;
        float4 x = *(const float4*)(w_v + (size_t)(e0 + el) * Dd + n0 + jq * 4);
        Bs[(jq * 4 + 0) * 32 + el] = (bf16)x.x;
        Bs[(jq * 4 + 1) * 32 + el] = (bf16)x.y;
        Bs[(jq * 4 + 2) * 32 + el] = (bf16)x.z;
        Bs[(jq * 4 + 3) * 32 + el] = (bf16)x.w;
      }
      __syncthreads();
      bf16x8 af[2], bfr[2];
#pragma unroll
      for (int i = 0; i < 2; i++)
        af[i] = *(const bf16x8*)(As + (wm * 32 + i * 16 + (lane & 15)) * 32 + (lane >> 4) * 8);
#pragma unroll
      for (int j = 0; j < 2; j++)
        bfr[j] = *(const bf16x8*)(Bs + (wn * 32 + j * 16 + (lane & 15)) * 32 + (lane >> 4) * 8);
#pragma unroll
      for (int i = 0; i < 2; i++)
#pragma unroll
        for (int j = 0; j < 2; j++)
          acc[i][j] = __builtin_amdgcn_mfma_f32_16x16x32_bf16(af[i], bfr[j], acc[i][j], 0, 0, 0);
    }
#pragma unroll
    for (int i = 0; i < 2; i++)
#pragma unroll
      for (int j = 0; j < 2; j++) {
        int jj = n0 + wn * 32 + j * 16 + (lane & 15);
        int dB = m0 + wm * 32 + i * 16 + ((lane >> 4) << 2);
#pragma unroll
        for (int r = 0; r < 4; r++)
          w_ov[(size_t)(dB + r) * Dd + jj] = (bf16)acc[i][j][r];
      }
  } else {
    // ---- bsum[d] = b_o[d] + sum_e W_o[d][e] * b_v[e]
    int d = (blk - BV0) * 256 + tid;
    float s = b_o[d];
    for (int e = 0; e < Dd; e += 4) {
      float4 wo = *(const float4*)(w_o + (size_t)d * Dd + e);
      float4 bv = *(const float4*)(b_v + e);
      s += wo.x * bv.x + wo.y * bv.y + wo.z * bv.z + wo.w * bv.w;
    }
    bsum[d] = s;
  }
}

// ---- Lx[r][:] = sum_j val_j * x0T[col_j][:].  One WAVE per row; lane holds
// 4 batch elems (bf16x4) -> one gather = full 512 B row. 4-way unroll (MLP).
__global__ __launch_bounds__(256) void k_lx(const bf16x4* __restrict__ x0T4,
                                            const int* __restrict__ counts,
                                            const int2* __restrict__ ents,
                                            bf16x4* __restrict__ Lx4) {
  int w = threadIdx.x >> 6, lane = threadIdx.x & 63;
  int r = blockIdx.x * 4 + w;
  __shared__ int2 esm[4][64];
  int cnt = counts[r];
  const int2* ep = ents + (size_t)r * SLOT;
  f32x4 a = {0.f, 0.f, 0.f, 0.f}, b = {0.f, 0.f, 0.f, 0.f};
  f32x4 c = {0.f, 0.f, 0.f, 0.f}, d = {0.f, 0.f, 0.f, 0.f};
  for (int base = 0; base < cnt; base += 64) {
    int m = cnt - base; if (m > 64) m = 64;
    if (lane < m) esm[w][lane] = ep[base + lane];
    int i = 0;
    for (; i + 3 < m; i += 4) {
      int2 e0 = esm[w][i], e1 = esm[w][i + 1], e2 = esm[w][i + 2], e3 = esm[w][i + 3];
      bf16x4 x0v = x0T4[(size_t)e0.x * 64 + lane];
      bf16x4 x1v = x0T4[(size_t)e1.x * 64 + lane];
      bf16x4 x2v = x0T4[(size_t)e2.x * 64 + lane];
      bf16x4 x3v = x0T4[(size_t)e3.x * 64 + lane];
      float v0 = __int_as_float(e0.y), v1 = __int_as_float(e1.y);
      float v2 = __int_as_float(e2.y), v3 = __int_as_float(e3.y);
#pragma unroll
      for (int q = 0; q < 4; q++) {
        a[q] += v0 * (float)x0v[q];
        b[q] += v1 * (float)x1v[q];
        c[q] += v2 * (float)x2v[q];
        d[q] += v3 * (float)x3v[q];
      }
    }
    for (; i < m; i++) {
      int2 e0 = esm[w][i];
      bf16x4 x0v = x0T4[(size_t)e0.x * 64 + lane];
      float v0 = __int_as_float(e0.y);
#pragma unroll
      for (int q = 0; q < 4; q++) a[q] += v0 * (float)x0v[q];
    }
  }
  bf16x4 o;
#pragma unroll
  for (int q = 0; q < 4; q++) o[q] = (bf16)(a[q] + b[q] + c[q] + d[q]);
  Lx4[(size_t)r * 64 + lane] = o;
}

// ---------------- x_t[b][n] = x0[b][n] - 0.5*t[b]*Lx[n][b]   (bf16, B-major)
__global__ __launch_bounds__(256) void k_combine(const float* __restrict__ x0,
                                                 const bf16* __restrict__ Lx,
                                                 const float* __restrict__ t,
                                                 bf16* __restrict__ xt) {
  __shared__ float lxs[64][65];
  int n0 = blockIdx.x * 64, b0 = blockIdx.y * 64;
  int tx = threadIdx.x & 63, ty = threadIdx.x >> 6;
#pragma unroll
  for (int i = 0; i < 16; i++) {
    int nl = ty * 16 + i;
    lxs[nl][tx] = (float)Lx[(size_t)(n0 + nl) * Bb + b0 + tx];
  }
  __syncthreads();
#pragma unroll
  for (int i = 0; i < 16; i++) {
    int bl = ty * 16 + i;
    int b  = b0 + bl;
    float tc = t[b] * 0.5f;   // T_MAX
    float v = x0[(size_t)b * Nn + n0 + tx] - tc * lxs[tx][bl];
    xt[(size_t)b * Nn + n0 + tx] = (bf16)v;
  }
}

// ------------------------------------------------------------- bf16 TN GEMM
// C[m][n] = sum_k A[m][k]*Bm[n][k].
//   MODE 0: store fp32 split-K partial at z*MN
//   MODE 1: direct bf16 store of acc+bias (ACT=1: exact gelu) -> C is bf16*
//   MODE 2: fused loss sum((C+bias-x0)^2), last wave writes final mean
//   BF32 : B matrix is fp32 in global; convert to bf16 during LDS staging
template <int BM, int BN, int MODE, int ACT = 0, int BF32 = 0>
__global__ __launch_bounds__(256) void gemm_tn(
    const bf16* __restrict__ A, const void* __restrict__ Bmv,
    float* __restrict__ C, int N, int K, int kLen, int MN,
    const float* __restrict__ bias, const float* __restrict__ x0,
    float* __restrict__ lossOut, float* __restrict__ finalOut, int nWaves) {
  constexpr int WM = BM / 2, WN = BN / 2, FM = WM / 16, FN = WN / 16;
  constexpr int PA = (BM * 64) / 4096, PB = (BN * 64) / 4096;
  __shared__ __align__(16) bf16 As[BM * 32];
  __shared__ __align__(16) bf16 Bs[BN * 32];
  const int tid = threadIdx.x;
  const int lane = tid & 63, w = tid >> 6;
  const int wm = w >> 1, wn = w & 1;
  const int mBase = blockIdx.x * BM, nBase = blockIdx.y * BN;
  const int k0 = blockIdx.z * kLen;

  f32x4 acc[FM][FN];
#pragma unroll
  for (int i = 0; i < FM; i++)
#pragma unroll
    for (int j = 0; j < FN; j++) acc[i][j] = {0.f, 0.f, 0.f, 0.f};

  for (int kk = 0; kk < kLen; kk += 32) {
    const int k = k0 + kk;
    __syncthreads();
#pragma unroll
    for (int p = 0; p < PA; p++) {
      int u = p * 256 + tid;  // == p*256 + w*64 + lane
      gload16(A + (size_t)(mBase + (u >> 2)) * K + k + (u & 3) * 8,
              (char*)As + p * 4096 + w * 1024);
    }
    if constexpr (BF32) {
      const float* Bf = (const float*)Bmv;
#pragma unroll
      for (int p = 0; p < BN * 32 / 1024; p++) {
        int u = p * 256 + tid;
        int row = u >> 3, sub = u & 7;
        float4 x = *(const float4*)(Bf + (size_t)(nBase + row) * K + k + sub * 4);
        bf16x4 o;
        o[0] = (bf16)x.x; o[1] = (bf16)x.y; o[2] = (bf16)x.z; o[3] = (bf16)x.w;
        *(bf16x4*)(Bs + row * 32 + sub * 4) = o;
      }
    } else {
      const bf16* Bm = (const bf16*)Bmv;
#pragma unroll
      for (int p = 0; p < PB; p++) {
        int u = p * 256 + tid;
        gload16(Bm + (size_t)(nBase + (u >> 2)) * K + k + (u & 3) * 8,
                (char*)Bs + p * 4096 + w * 1024);
      }
    }
    __syncthreads();
    bf16x8 af[FM], bfr[FN];
#pragma unroll
    for (int i = 0; i < FM; i++)
      af[i] = *(const bf16x8*)(As + (wm * WM + i * 16 + (lane & 15)) * 32 + (lane >> 4) * 8);
#pragma unroll
    for (int j = 0; j < FN; j++)
      bfr[j] = *(const bf16x8*)(Bs + (wn * WN + j * 16 + (lane & 15)) * 32 + (lane >> 4) * 8);
#pragma unroll
    for (int i = 0; i < FM; i++)
#pragma unroll
      for (int j = 0; j < FN; j++)
        acc[i][j] = __builtin_amdgcn_mfma_f32_16x16x32_bf16(af[i], bfr[j], acc[i][j], 0, 0, 0);
  }

  if constexpr (MODE == 0) {
    float* Cz = C + (size_t)blockIdx.z * MN;
#pragma unroll
    for (int i = 0; i < FM; i++)
#pragma unroll
      for (int j = 0; j < FN; j++) {
        int n  = nBase + wn * WN + j * 16 + (lane & 15);
        int mB = mBase + wm * WM + i * 16 + ((lane >> 4) << 2);
#pragma unroll
        for (int r = 0; r < 4; r++)
          Cz[(size_t)(mB + r) * N + n] = acc[i][j][r];
      }
  } else if constexpr (MODE == 1) {
    bf16* Cb = (bf16*)C;
#pragma unroll
    for (int i = 0; i < FM; i++)
#pragma unroll
      for (int j = 0; j < FN; j++) {
        int n  = nBase + wn * WN + j * 16 + (lane & 15);
        float bo = bias[n];
        int mB = mBase + wm * WM + i * 16 + ((lane >> 4) << 2);
#pragma unroll
        for (int r = 0; r < 4; r++) {
          float x = acc[i][j][r] + bo;
          if constexpr (ACT == 1)
            x = 0.5f * x * (1.f + erff(x * 0.70710678118654752f));
          Cb[(size_t)(mB + r) * N + n] = (bf16)x;
        }
      }
  } else {
    float lsum = 0.f;
#pragma unroll
    for (int i = 0; i < FM; i++)
#pragma unroll
      for (int j = 0; j < FN; j++) {
        int n  = nBase + wn * WN + j * 16 + (lane & 15);
        float bo = bias[n];
        int mB = mBase + wm * WM + i * 16 + ((lane >> 4) << 2);
#pragma unroll
        for (int r = 0; r < 4; r++) {
          float d = acc[i][j][r] + bo - x0[(size_t)(mB + r) * N + n];
          lsum += d * d;
        }
      }
    for (int off = 32; off > 0; off >>= 1) lsum += __shfl_down(lsum, off, 64);
    if (lane == 0) {
      atomicAdd(lossOut, lsum);
      __threadfence();
      unsigned prev = atomicAdd((unsigned*)(lossOut + 1), 1u);
      if ((int)prev == nWaves - 1) {
        float tot = atomicAdd(lossOut, 0.f);  // atomic read-back
        finalOut[0] = tot * (1.f / 4194304.f);
      }
    }
  }
}

// ------------- h = sum_NS partials + b_in + time-embed; write fp32 + bf16
template <int NS>
__global__ __launch_bounds__(512) void k_epi_h(const float* __restrict__ P,
                                               const float* __restrict__ t,
                                               const float* __restrict__ W_t1,
                                               const float* __restrict__ b_t1,
                                               const float* __restrict__ W_t2,
                                               const float* __restrict__ b_t2,
                                               const float* __restrict__ b_in,
                                               float* __restrict__ h_f32,
                                               bf16* __restrict__ h_b) {
  int b = blockIdx.x, d = threadIdx.x;
  __shared__ float s[32];
  if (d < 32) {
    float z = t[b] * W_t1[d] + b_t1[d];   // t_norm == t
    s[d] = z / (1.f + expf(-z));          // silu
  }
  __syncthreads();
  int i = b * Dd + d;
  float v = b_in[d] + b_t2[d];
#pragma unroll
  for (int sp = 0; sp < NS; sp++) v += P[sp * (Bb * Dd) + i];
#pragma unroll
  for (int j = 0; j < 32; j++) v += s[j] * W_t2[d * 32 + j];
  h_f32[i] = v;
  h_b[i] = (bf16)v;
}

// -------- LayerNorm over D=512: x = base + sum_NS add + bias; y = LN(x)*g+be
template <int NS>
__global__ __launch_bounds__(512) void k_ln(const float* __restrict__ base,
                                            const float* __restrict__ add,
                                            const float* __restrict__ bias,
                                            const float* __restrict__ g,
                                            const float* __restrict__ be,
                                            float* __restrict__ out_f32,
                                            bf16* __restrict__ out_b) {
  int b = blockIdx.x, d = threadIdx.x;
  __shared__ float red[16];
  int i = b * Dd + d;
  float x = base[i] + bias[d];
#pragma unroll
  for (int sp = 0; sp < NS; sp++) x += add[sp * (Bb * Dd) + i];
  int w = d >> 6, lane = d & 63;
  float s = x;
  for (int off = 32; off > 0; off >>= 1) s += __shfl_down(s, off, 64);
  if (lane == 0) red[w] = s;
  __syncthreads();
  if (d == 0) {
    float tot = 0.f;
    for (int q = 0; q < 8; q++) tot += red[q];
    red[8] = tot * (1.f / 512.f);
  }
  __syncthreads();
  float mu = red[8];
  float c = x - mu;
  float s2 = c * c;
  for (int off = 32; off > 0; off >>= 1) s2 += __shfl_down(s2, off, 64);
  if (lane == 0) red[w] = s2;
  __syncthreads();
  if (d == 0) {
    float tot = 0.f;
    for (int q = 0; q < 8; q++) tot += red[q];
    red[8] = tot * (1.f / 512.f);
  }
  __syncthreads();
  float var = red[8];
  float y = c * rsqrtf(var + 1e-5f) * g[d] + be[d];
  if (out_f32) out_f32[i] = y;
  out_b[i] = (bf16)y;
}

// ======================================================================= host
extern "C" void kernel_launch(void* const* d_in, const int* in_sizes, int n_in,
                              void* d_out, int out_size, void* d_ws, size_t ws_size,
                              hipStream_t stream) {
  const float* x0    = (const float*)d_in[0];
  const float* t     = (const float*)d_in[1];
  const float* Lv    = (const float*)d_in[2];
  const float* W_in  = (const float*)d_in[3];
  const float* b_in  = (const float*)d_in[4];
  const float* W_out = (const float*)d_in[5];
  const float* b_out = (const float*)d_in[6];
  const float* W_qkv = (const float*)d_in[7];
  const float* b_qkv = (const float*)d_in[8];
  const float* W_o   = (const float*)d_in[9];
  const float* b_o   = (const float*)d_in[10];
  const float* g1    = (const float*)d_in[11];
  const float* be1   = (const float*)d_in[12];
  const float* g2    = (const float*)d_in[13];
  const float* be2   = (const float*)d_in[14];
  const float* W_f1  = (const float*)d_in[15];
  const float* b_f1  = (const float*)d_in[16];
  const float* W_f2  = (const float*)d_in[17];
  const float* b_f2  = (const float*)d_in[18];
  const float* W_t1  = (const float*)d_in[19];
  const float* b_t1  = (const float*)d_in[20];
  const float* W_t2  = (const float*)d_in[21];
  const float* b_t2  = (const float*)d_in[22];
  const int* L_rows  = (const int*)d_in[23];
  const int* L_cols  = (const int*)d_in[24];

  size_t off = 0;
  char* ws = (char*)d_ws;
  auto carve = [&](size_t bytes) -> void* {
    void* p = ws + off;
    off += (bytes + 255) & ~(size_t)255;
    return p;
  };

  bf16* W_ov_b   = (bf16*)carve((size_t)Dd * Dd * 2);
  bf16* W_f1_b   = (bf16*)carve((size_t)DFf * Dd * 2);
  bf16* W_f2_b   = (bf16*)carve((size_t)Dd * DFf * 2);
  float* bsum    = (float*)carve((size_t)Dd * 4);
  bf16* x0T_b    = (bf16*)carve((size_t)Nn * Bb * 2);
  bf16* Lx_b     = (bf16*)carve((size_t)Nn * Bb * 2);
  bf16* xt_b     = (bf16*)carve((size_t)Bb * Nn * 2);
  float* p_h     = (float*)carve((size_t)32 * Bb * Dd * 4);   // 16 MB
  float* p_at    = (float*)carve((size_t)8 * Bb * Dd * 4);    //  4 MB
  float* p_f2    = (float*)carve((size_t)8 * Bb * Dd * 4);    //  4 MB
  float* h_f32   = (float*)carve((size_t)Bb * Dd * 4);
  bf16* h_b      = (bf16*)carve((size_t)Bb * Dd * 2);
  float* hln_f32 = (float*)carve((size_t)Bb * Dd * 4);
  bf16* hln_b    = (bf16*)carve((size_t)Bb * Dd * 2);
  bf16* f1_b     = (bf16*)carve((size_t)Bb * DFf * 2);
  bf16* h2_b     = (bf16*)carve((size_t)Bb * Dd * 2);
  int* counts    = (int*)carve((size_t)Nn * 4);
  float* lossw   = (float*)carve(256);                        // [0]=sum [1]=ticket
  int2* ents     = (int2*)carve((size_t)Nn * SLOT * 8);       // 16.8 MB
  (void)in_sizes; (void)n_in; (void)out_size; (void)ws_size; (void)Lv;

  // counts + lossw adjacent: one memset covers both
  hipMemsetAsync(counts, 0, (size_t)Nn * 4 + 256, stream);

  // prep: bucket | transpose | FF cvt | W_ov mini-gemm | bsum (one kernel)
  k_prep<<<PREP_BLKS, 256, 0, stream>>>(
      W_qkv + (size_t)2 * Dd * Dd, W_o, W_f1, W_f2, W_f1_b, W_f2_b,
      W_ov_b, b_o, b_qkv + 2 * Dd, bsum,
      x0, x0T_b, L_rows, L_cols, Lv, counts, ents);

  k_lx<<<Nn / 4, 256, 0, stream>>>((const bf16x4*)x0T_b, counts, ents,
                                   (bf16x4*)Lx_b);
  k_combine<<<dim3(256, 4), 256, 0, stream>>>(x0, Lx_b, t, xt_b);

  // h = x_t @ W_in^T   (M=256,N=512,K=16384, split-K=32 -> 256 blocks)
  gemm_tn<128, 128, 0, 0, 1><<<dim3(2, 4, 32), 256, 0, stream>>>(
      xt_b, W_in, p_h, Dd, Nn, 512, Bb * Dd, nullptr, nullptr, nullptr, nullptr, 0);
  k_epi_h<32><<<Bb, 512, 0, stream>>>(p_h, t, W_t1, b_t1, W_t2, b_t2, b_in,
                                      h_f32, h_b);

  // attn = h @ W_ov^T  (v+o fused; split-K=8 -> 256 blocks)
  gemm_tn<64, 64, 0><<<dim3(4, 8, 8), 256, 0, stream>>>(
      h_b, W_ov_b, p_at, Dd, Dd, 64, Bb * Dd, nullptr, nullptr, nullptr, nullptr, 0);
  k_ln<8><<<Bb, 512, 0, stream>>>(h_f32, p_at, bsum, g1, be1, hln_f32, hln_b);

  // ff1 = gelu(hln @ W_f1^T + b_f1)  (fused bf16 epilogue, 128 blocks)
  gemm_tn<64, 64, 1, 1><<<dim3(4, 32, 1), 256, 0, stream>>>(
      hln_b, W_f1_b, (float*)f1_b, DFf, Dd, 512, 0, b_f1, nullptr, nullptr, nullptr, 0);

  // ff2 = ff1 @ W_f2^T  (K=2048, split-K=8 -> 256 blocks)
  gemm_tn<64, 64, 0><<<dim3(4, 8, 8), 256, 0, stream>>>(
      f1_b, W_f2_b, p_f2, Dd, DFf, 256, Bb * Dd, nullptr, nullptr, nullptr, nullptr, 0);
  k_ln<8><<<Bb, 512, 0, stream>>>(hln_f32, p_f2, b_f2, g2, be2, nullptr, h2_b);

  // pred = h2 @ W_out^T + b_out, fused loss + final mean (ticket finish)
  gemm_tn<128, 128, 2, 0, 1><<<dim3(2, 128, 1), 256, 0, stream>>>(
      h2_b, W_out, nullptr, Nn, Dd, 512, 0, b_out, x0, lossw,
      (float*)d_out, 2 * 128 * 4);
}